// Round 7
// baseline (115.631 us; speedup 1.0000x reference)
//
#include <hip/hip_runtime.h>

// out[b,o] = x@W1 + quad + bias,  quad[b,o] = sum_ij x[b,i] x[b,j] W2[i,j,o].
// Factored + scale-early: quad[b,o] = sum_i sum_jw x[b,i] * mfma(x[b,jw], W2t[i,jw]).
// Pass 1 (wtr): W2 -> W2t[i][o:16][j:800] bf16 (zero-padded) so ALL main-kernel
// loads are contiguous 16B. Pass 2 (zgemm): NO LDS, NO barriers; A held entirely
// in registers (statically indexed), B streamed from L3, tmp=mfma(a,b,0) scaled
// by f32 x_i into a tiny accumulator. 392 blocks x 4 waves, ISLAB=8.

#define D_IN 784
#define JP 800           // j padded to 25*32
#define MB 512
#define OUTN 10
#define OP 16            // o padded to MFMA n=16
#define NJW 25
#define ISLAB 8
#define NSLAB 98         // 784 / ISLAB

typedef unsigned short ushort_t;
typedef unsigned int uint_t;
typedef __attribute__((ext_vector_type(4))) float f32x4;
typedef __attribute__((ext_vector_type(8))) __bf16 bf16x8;

__device__ __forceinline__ ushort_t f2bf(float f) {
  uint_t u = __builtin_bit_cast(uint_t, f);
  u += 0x7FFFu + ((u >> 16) & 1u);
  return (ushort_t)(u >> 16);
}

// ---- prep: x f32 [512][784] -> xb bf16 [512][800] (padded) + xT f32 [784][512] ----
__global__ __launch_bounds__(256) void prep_kernel(const float* __restrict__ x,
                                                   ushort_t* __restrict__ xb,
                                                   float* __restrict__ xT) {
  __shared__ float tile[32][33];
  const int j0 = blockIdx.x * 32;             // 25 tiles (covers 800)
  const int b0 = blockIdx.y * 32;             // 16 tiles
  const int tx = threadIdx.x, ty = threadIdx.y;
#pragma unroll
  for (int q = 0; q < 4; ++q) {
    int b = b0 + ty + 8 * q;
    int j = j0 + tx;
    float v = (j < D_IN) ? x[(size_t)b * D_IN + j] : 0.f;
    xb[(size_t)b * JP + j] = f2bf(v);
    tile[ty + 8 * q][tx] = v;
  }
  __syncthreads();
#pragma unroll
  for (int q = 0; q < 4; ++q) {
    int jj = ty + 8 * q;
    int j = j0 + jj;
    if (j < D_IN) xT[(size_t)j * MB + b0 + tx] = tile[tx][jj];
  }
}

// ---- pass 1: W2v[i*7840 + j*10 + o] f32 -> W2t[(i*16+o)*800 + j] bf16 ----
// One block per i. Read 31.4 KB coalesced -> LDS -> write 16 rows x 1600 B.
__global__ __launch_bounds__(256) void wtr_kernel(const float* __restrict__ W2v,
                                                  ushort_t* __restrict__ W2t) {
  __shared__ float wl[8016];                  // 7840 + pad (OOB-lane safety)
  const int i = blockIdx.x, t = threadIdx.x;
  const float* src = W2v + (size_t)i * 7840;
  for (int c = t; c < 1960; c += 256)
    ((f32x4*)wl)[c] = ((const f32x4*)src)[c];
  __syncthreads();
  const int o = t & 15, jq0 = t >> 4;
  ushort_t* drow = W2t + ((size_t)i * OP + o) * JP;
  for (int jq = jq0; jq < 100; jq += 16) {
    int j0 = jq * 8;
    uint_t pk[4];
#pragma unroll
    for (int h = 0; h < 4; ++h) {
      int ja = j0 + 2 * h, jb = ja + 1;
      float v0 = (o < OUTN && ja < D_IN) ? wl[ja * 10 + o] : 0.f;
      float v1 = (o < OUTN && jb < D_IN) ? wl[jb * 10 + o] : 0.f;
      pk[h] = (uint_t)f2bf(v0) | ((uint_t)f2bf(v1) << 16);
    }
    uint4 u; u.x = pk[0]; u.y = pk[1]; u.z = pk[2]; u.w = pk[3];
    *(uint4*)(drow + j0) = u;
  }
}

// ---- linear part + bias: out[b,:] = x[b,:] @ W1 + bias ----
__global__ __launch_bounds__(256) void init_out_kernel(const float* __restrict__ x,
                                                       const float* __restrict__ W,
                                                       const float* __restrict__ bias,
                                                       float* __restrict__ out) {
  int b = blockIdx.x;
  int t = threadIdx.x;
  __shared__ float part[OUTN];
  if (t < OUTN) part[t] = bias[t];
  __syncthreads();
  float acc[OUTN];
#pragma unroll
  for (int o = 0; o < OUTN; ++o) acc[o] = 0.f;
  for (int i = t; i < D_IN; i += 256) {
    float xv = x[(size_t)b * D_IN + i];
#pragma unroll
    for (int o = 0; o < OUTN; ++o) acc[o] += xv * W[i * OUTN + o];
  }
#pragma unroll
  for (int o = 0; o < OUTN; ++o) {
    float v = acc[o];
#pragma unroll
    for (int s = 32; s > 0; s >>= 1) v += __shfl_down(v, s);
    if ((t & 63) == 0) atomicAdd(&part[o], v);
  }
  __syncthreads();
  if (t < OUTN) out[(size_t)b * OUTN + t] = part[t];
}

// ---- pass 2: main quad kernel. No LDS, no barriers. ----
// Wave = 32 rows (2 m-frags); block = 4 waves = 128 rows; grid (98 slabs, 4 rowblocks).
// A = xb rows, held in 200 VGPRs (fully static indexing). B = W2t streamed.
template <int USE_WS>
__global__ __launch_bounds__(256, 2) void zgemm_kernel(const ushort_t* __restrict__ xb,
                                                       const ushort_t* __restrict__ W2t,
                                                       const float* __restrict__ xT,
                                                       float* __restrict__ dst) {
  const int tid = threadIdx.x;
  const int w = tid >> 6, l = tid & 63, lr = l & 15, lh = l >> 4;
  const int i0 = blockIdx.x * ISLAB;
  const int r0 = blockIdx.y * 128 + w * 32;   // wave's 32 rows

  // A fragments for all 25 j-windows x 2 m-frags: 50 x 16B loads, lives in regs.
  bf16x8 a[2][NJW];
#pragma unroll
  for (int mf = 0; mf < 2; ++mf)
#pragma unroll
    for (int jw = 0; jw < NJW; ++jw)
      a[mf][jw] = *(const bf16x8*)(xb + (size_t)(r0 + mf * 16 + lr) * JP + jw * 32 + lh * 8);

  const f32x4 zero = {0.f, 0.f, 0.f, 0.f};
  f32x4 q0 = zero, q1 = zero;
  const ushort_t* wb = W2t + ((size_t)i0 * OP + lr) * JP + lh * 8;
  const float* xtb = xT + (size_t)i0 * MB + r0 + lh * 4;

#pragma unroll 2
  for (int ii = 0; ii < ISLAB; ++ii) {
    f32x4 xs0 = *(const f32x4*)(xtb + ii * MB);        // x[rows of mf0][i0+ii]
    f32x4 xs1 = *(const f32x4*)(xtb + ii * MB + 16);   // x[rows of mf1][i0+ii]
    const ushort_t* wr = wb + (size_t)ii * (OP * JP);
#pragma unroll
    for (int jw = 0; jw < NJW; ++jw) {
      bf16x8 bf = *(const bf16x8*)(wr + jw * 32);      // 16B contiguous, L3-hot
      f32x4 t0 = __builtin_amdgcn_mfma_f32_16x16x32_bf16(a[0][jw], bf, zero, 0, 0, 0);
      f32x4 t1 = __builtin_amdgcn_mfma_f32_16x16x32_bf16(a[1][jw], bf, zero, 0, 0, 0);
      q0 += xs0 * t0;                                  // scale-early: 4 fma each
      q1 += xs1 * t1;
    }
  }

  // C/D: col = lane&15 (= o), row = (lane>>4)*4 + r
  if (lr < OUTN) {
    if (USE_WS) {
      float* wp = dst + (size_t)blockIdx.x * (MB * OUTN);
#pragma unroll
      for (int r = 0; r < 4; ++r) {
        wp[(r0 + 4 * lh + r) * OUTN + lr] = q0[r];
        wp[(r0 + 16 + 4 * lh + r) * OUTN + lr] = q1[r];
      }
    } else {
#pragma unroll
      for (int r = 0; r < 4; ++r) {
        atomicAdd(&dst[(size_t)(r0 + 4 * lh + r) * OUTN + lr], q0[r]);
        atomicAdd(&dst[(size_t)(r0 + 16 + 4 * lh + r) * OUTN + lr], q1[r]);
      }
    }
  }
}

// ---- reduce: out[idx] += sum over 98 slab partials ----
__global__ __launch_bounds__(256) void reduce_kernel(const float* __restrict__ ws,
                                                     float* __restrict__ out) {
  int idx = blockIdx.x * 256 + threadIdx.x;   // 5120
  if (idx >= MB * OUTN) return;
  const float* p = ws + idx;
  float s0 = 0.f, s1 = 0.f;
#pragma unroll 1
  for (int c = 0; c + 2 <= NSLAB; c += 2) {
    s0 += p[(size_t)(c + 0) * (MB * OUTN)];
    s1 += p[(size_t)(c + 1) * (MB * OUTN)];
  }
  out[idx] += s0 + s1;
}

extern "C" void kernel_launch(void* const* d_in, const int* in_sizes, int n_in,
                              void* d_out, int out_size, void* d_ws, size_t ws_size,
                              hipStream_t stream) {
  const float* x = (const float*)d_in[0];     // 512 x 784
  const float* W = (const float*)d_in[1];     // 615440 x 10
  const float* bias = (const float*)d_in[2];  // 10
  float* out = (float*)d_out;                 // 512 x 10 f32

  const size_t w2t_b = (size_t)D_IN * OP * JP * 2;   // 20,070,400
  const size_t xb_b = (size_t)MB * JP * 2;           // 819,200
  const size_t xt_b = (size_t)D_IN * MB * 4;         // 1,605,632
  const size_t part_b = (size_t)NSLAB * MB * OUTN * 4; // 2,007,040

  ushort_t* W2t = (ushort_t*)d_ws;
  ushort_t* xb = (ushort_t*)((char*)d_ws + w2t_b);
  float* xT = (float*)((char*)d_ws + w2t_b + xb_b);
  float* wsp = (float*)((char*)d_ws + w2t_b + xb_b + xt_b);

  prep_kernel<<<dim3(NJW, 16), dim3(32, 8), 0, stream>>>(x, xb, xT);
  wtr_kernel<<<D_IN, 256, 0, stream>>>(W + D_IN * OUTN, W2t);
  init_out_kernel<<<MB, 256, 0, stream>>>(x, W, bias, out);

  if (ws_size >= w2t_b + xb_b + xt_b + part_b) {
    zgemm_kernel<1><<<dim3(NSLAB, 4), 256, 0, stream>>>(xb, W2t, xT, wsp);
    reduce_kernel<<<(MB * OUTN + 255) / 256, 256, 0, stream>>>(wsp, out);
  } else {
    zgemm_kernel<0><<<dim3(NSLAB, 4), 256, 0, stream>>>(xb, W2t, xT, out);
  }
}